// Round 2
// baseline (815.867 us; speedup 1.0000x reference)
//
#include <hip/hip_runtime.h>
#include <hip/hip_bf16.h>

// SpookyNet Performer-style attention, N=262144, d=128, m=256, f32 in/out.
// out = (Qp·Kp) * V / (Qp·sum_n Kp + 1e-8), Qp/Kp = (exp(U - h - max) + 1e-4)/16
// U matmuls via f16 MFMA (16x16x32), everything else f32.
//
// R2: persistent blocks (512 = 2/CU), each stages omega ONCE then loops over
// 8 tiles with ZERO barriers in the loop:
//  - k_kstats L/P statistics are per-WAVE with an online running max
//    (Pw *= exp(Lold-Lnew)), so no cross-wave reduction; 2048 groups total.
//  - k_main epilogue is wave-local (scales broadcast via shfl), no scale_lds.
//  - single-buffer register prefetch: convert last tile's arrived float4s to
//    f16 frags, then immediately re-issue the same (dead) registers as next
//    tile's loads -> HBM loads in flight across the whole iteration body.
//  - V issued right after the MFMA loop; latency hides under softmax VALU.

typedef _Float16 f16x8 __attribute__((ext_vector_type(8)));
typedef float f32x4 __attribute__((ext_vector_type(4)));

#define D_QK 128
#define M_F  256
#define OMT_HALVES 32768   // 16 t * 4 ks * 64 lanes * 8 halves = 64 KB
#define GBLK 512           // persistent blocks (2 per CU)

constexpr float D4      = 0.29730177875068026f;   // 128^-0.25
constexpr float H_SCALE = 0.044194173824159216f;  // 1/(2*sqrt(128))

__device__ __forceinline__ unsigned f2key(float f) {
  unsigned b = __float_as_uint(f);
  return (b & 0x80000000u) ? ~b : (b | 0x80000000u);   // monotone total order on floats
}
__device__ __forceinline__ float key2f(unsigned k) {
  return (k & 0x80000000u) ? __uint_as_float(k & 0x7fffffffu) : __uint_as_float(~k);
}

__device__ __forceinline__ f32x4 mfma16(f16x8 a, f16x8 b, f32x4 c) {
  return __builtin_amdgcn_mfma_f32_16x16x32_f16(a, b, c, 0, 0, 0);
}

// Convert 8 raw f32 (two float4 regs) to an f16 A-fragment, accumulate sum-sq.
__device__ __forceinline__ void conv_frag(const float4& x0, const float4& x1,
                                          f16x8& a, float& h) {
  h += x0.x*x0.x + x0.y*x0.y + x0.z*x0.z + x0.w*x0.w
     + x1.x*x1.x + x1.y*x1.y + x1.z*x1.z + x1.w*x1.w;
  a[0] = (_Float16)(x0.x * D4); a[1] = (_Float16)(x0.y * D4);
  a[2] = (_Float16)(x0.z * D4); a[3] = (_Float16)(x0.w * D4);
  a[4] = (_Float16)(x1.x * D4); a[5] = (_Float16)(x1.y * D4);
  a[6] = (_Float16)(x1.z * D4); a[7] = (_Float16)(x1.w * D4);
}

// B-fragment LDS read: lane-contiguous, conflict-free.
__device__ __forceinline__ f16x8 bfrag(const _Float16* om_lds, int t, int ks, int lane) {
  return *(const f16x8*)&om_lds[(((t << 2) | ks) << 9) + (lane << 3)];
}

// ---------------------------------------------------------------------------
// k_prep: omega (d,m) f32 -> omt fragment-major f16; init S=0, Mkey=0.
extern "C" __global__ void k_prep(const float* __restrict__ om, _Float16* __restrict__ omt,
                                  float* __restrict__ S, unsigned* __restrict__ Mkey) {
  int i = blockIdx.x * 256 + threadIdx.x;           // grid = 128 blocks
  if (i < OMT_HALVES) {
    int t = i >> 11, ks = (i >> 9) & 3, l = (i >> 3) & 63, j = i & 7;
    int d = ks * 32 + ((l >> 4) << 3) + j;
    int m = t * 16 + (l & 15);
    omt[i] = (_Float16)om[d * M_F + m];
  }
  if (blockIdx.x == 0) {
    S[threadIdx.x] = 0.f;
    if (threadIdx.x == 0) *Mkey = 0u;
  }
}

// ---------------------------------------------------------------------------
// k_kstats: persistent. Per wave-group (16 rows x T tiles = 128 rows):
// running max Lw over raw U, Pw[m] = sum_rows exp(U - h - Lw) (online rescale).
__global__ __launch_bounds__(256, 2) void k_kstats(
    const float* __restrict__ K, const _Float16* __restrict__ omt,
    float* __restrict__ Lout, float* __restrict__ Pout, unsigned* __restrict__ Mkey,
    int T) {
  __shared__ __align__(16) _Float16 om_lds[OMT_HALVES];   // 64 KB
  int tid = threadIdx.x;
  int w = tid >> 6, lane = tid & 63, q = lane >> 4, c = lane & 15;

  // stage omega once (linear copy, conflict-free)
  const float4* osrc = (const float4*)omt;
  float4* odst = (float4*)om_lds;
#pragma unroll
  for (int i = 0; i < 16; ++i) odst[tid + i * 256] = osrc[tid + i * 256];

  size_t row0 = (size_t)blockIdx.x * T * 64 + w * 16 + c;
  const float4* kptr = (const float4*)(K + row0 * D_QK) + q * 2;

  // prefetch tile 0
  float4 kf[8];
#pragma unroll
  for (int ks = 0; ks < 4; ++ks) {
    kf[ks * 2] = kptr[ks * 8]; kf[ks * 2 + 1] = kptr[ks * 8 + 1];
  }

  float Pw[16];
#pragma unroll
  for (int t = 0; t < 16; ++t) Pw[t] = 0.f;
  float Lrun = -1e30f;

  __syncthreads();                           // omega staged; the ONLY barrier

  for (int it = 0; it < T; ++it) {
    // convert current tile (waits on last iter's loads)
    f16x8 ak[4];
    float hk = 0.f;
#pragma unroll
    for (int ks = 0; ks < 4; ++ks) conv_frag(kf[ks * 2], kf[ks * 2 + 1], ak[ks], hk);
    hk += __shfl_xor(hk, 16, 64);
    hk += __shfl_xor(hk, 32, 64);
    hk *= H_SCALE;

    // re-issue the (dead) kf regs as next tile's loads
    kptr += 2048;                            // 64 rows
    if (it + 1 < T) {
#pragma unroll
      for (int ks = 0; ks < 4; ++ks) {
        kf[ks * 2] = kptr[ks * 8]; kf[ks * 2 + 1] = kptr[ks * 8 + 1];
      }
    }

    const f32x4 zero = {0.f, 0.f, 0.f, 0.f};
    f32x4 cc[16];
#pragma unroll
    for (int t = 0; t < 16; ++t) cc[t] = zero;
#pragma unroll
    for (int t = 0; t < 16; ++t) {
#pragma unroll
      for (int ks = 0; ks < 4; ++ks) {
        f16x8 b = bfrag(om_lds, t, ks, lane);
        cc[t] = mfma16(ak[ks], b, cc[t]);
      }
    }

    float hr[4];
#pragma unroll
    for (int r = 0; r < 4; ++r) hr[r] = __shfl(hk, q * 4 + r, 64);

    // wave max over raw U (16 rows x 256 cols)
    float mx = cc[0][0];
#pragma unroll
    for (int t = 0; t < 16; ++t)
      mx = fmaxf(mx, fmaxf(fmaxf(cc[t][0], cc[t][1]), fmaxf(cc[t][2], cc[t][3])));
#pragma unroll
    for (int m = 1; m <= 32; m <<= 1) mx = fmaxf(mx, __shfl_xor(mx, m, 64));

    float newL = fmaxf(Lrun, mx);
    float fr = __expf(Lrun - newL);          // 0 on first iter (exp(-huge))

#pragma unroll
    for (int t = 0; t < 16; ++t) {
      float s = __expf(cc[t][0] - hr[0] - newL) + __expf(cc[t][1] - hr[1] - newL)
              + __expf(cc[t][2] - hr[2] - newL) + __expf(cc[t][3] - hr[3] - newL);
      s += __shfl_xor(s, 16, 64);
      s += __shfl_xor(s, 32, 64);            // col sum over this wave's 16 rows
      Pw[t] = Pw[t] * fr + s;
    }
    Lrun = newL;
  }

  int wid = blockIdx.x * 4 + w;
  if (q == 0) {
#pragma unroll
    for (int t = 0; t < 16; ++t) Pout[(size_t)wid * 256 + t * 16 + c] = Pw[t];
  }
  if (lane == 0) {
    Lout[wid] = Lrun;
    atomicMax(Mkey, f2key(Lrun));
  }
}

// ---------------------------------------------------------------------------
// k_combine: S[m] = sum_g exp(Lg - M) * P_g[m]; write M as float.
extern "C" __global__ void k_combine(const float* __restrict__ Lout, const float* __restrict__ Pout,
                                     const unsigned* __restrict__ Mkey, float* __restrict__ Mout,
                                     float* __restrict__ S) {
  float M = key2f(*Mkey);
  if (blockIdx.x == 0 && threadIdx.x == 0) *Mout = M;
  int g0 = blockIdx.x * 32;                 // grid = NG/32
  float acc = 0.f;
#pragma unroll
  for (int i = 0; i < 32; ++i) {
    int g = g0 + i;
    acc += __expf(Lout[g] - M) * Pout[(size_t)g * 256 + threadIdx.x];
  }
  atomicAdd(&S[threadIdx.x], acc);
}

// ---------------------------------------------------------------------------
// k_main: persistent. Per tile: U_Q and U_K (B-fragment shared), Qp/Kp, w,
// norm, out = (w/norm) * V. Fully wave-local; no barriers in the loop.
__global__ __launch_bounds__(256, 2) void k_main(
    const float* __restrict__ Q, const float* __restrict__ K, const float* __restrict__ V,
    const _Float16* __restrict__ omt, const float* __restrict__ Sws,
    const float* __restrict__ Mws, float* __restrict__ out, float epsN, int T) {
  __shared__ __align__(16) _Float16 om_lds[OMT_HALVES];   // 64 KB
  __shared__ float S_lds[256];
  int tid = threadIdx.x;
  int w = tid >> 6, lane = tid & 63, q = lane >> 4, c = lane & 15;

  const float4* osrc = (const float4*)omt;
  float4* odst = (float4*)om_lds;
#pragma unroll
  for (int i = 0; i < 16; ++i) odst[tid + i * 256] = osrc[tid + i * 256];
  S_lds[tid] = (Sws[tid] + epsN) * 0.0625f;   // true S (incl. N*eps, /sqrt(m))
  float Mglob = *Mws;

  size_t row0 = (size_t)blockIdx.x * T * 64 + w * 16 + c;
  const float4* qptr = (const float4*)(Q + row0 * D_QK) + q * 2;
  const float4* kptr = (const float4*)(K + row0 * D_QK) + q * 2;

  // prefetch tile 0
  float4 qf[8], kf[8];
#pragma unroll
  for (int ks = 0; ks < 4; ++ks) {
    qf[ks * 2] = qptr[ks * 8]; qf[ks * 2 + 1] = qptr[ks * 8 + 1];
    kf[ks * 2] = kptr[ks * 8]; kf[ks * 2 + 1] = kptr[ks * 8 + 1];
  }
  __syncthreads();                           // omega staged; the ONLY barrier

  for (int it = 0; it < T; ++it) {
    // convert current tile
    f16x8 aq[4], ak[4];
    float hq = 0.f, hk = 0.f;
#pragma unroll
    for (int ks = 0; ks < 4; ++ks) {
      conv_frag(qf[ks * 2], qf[ks * 2 + 1], aq[ks], hq);
      conv_frag(kf[ks * 2], kf[ks * 2 + 1], ak[ks], hk);
    }
    hq += __shfl_xor(hq, 16, 64); hq += __shfl_xor(hq, 32, 64); hq *= H_SCALE;
    hk += __shfl_xor(hk, 16, 64); hk += __shfl_xor(hk, 32, 64); hk *= H_SCALE;

    // re-issue the (dead) qf/kf regs as next tile's loads
    qptr += 2048; kptr += 2048;
    if (it + 1 < T) {
#pragma unroll
      for (int ks = 0; ks < 4; ++ks) {
        qf[ks * 2] = qptr[ks * 8]; qf[ks * 2 + 1] = qptr[ks * 8 + 1];
        kf[ks * 2] = kptr[ks * 8]; kf[ks * 2 + 1] = kptr[ks * 8 + 1];
      }
    }

    const f32x4 zero = {0.f, 0.f, 0.f, 0.f};
    f32x4 cq[16], ck[16];
#pragma unroll
    for (int t = 0; t < 16; ++t) { cq[t] = zero; ck[t] = zero; }
#pragma unroll
    for (int t = 0; t < 16; ++t) {
#pragma unroll
      for (int ks = 0; ks < 4; ++ks) {
        f16x8 b = bfrag(om_lds, t, ks, lane);
        cq[t] = mfma16(aq[ks], b, cq[t]);
        ck[t] = mfma16(ak[ks], b, ck[t]);
      }
    }

    // V for this tile (wave-local 16 rows); latency hides under softmax VALU
    size_t f4base = ((size_t)blockIdx.x * T + it) * 2048 + (size_t)w * 512;
    const float4* vp = (const float4*)V + f4base;
    float4 vf[8];
#pragma unroll
    for (int i = 0; i < 8; ++i) vf[i] = vp[i * 64 + lane];

    float hqr[4], hkr[4];
#pragma unroll
    for (int r = 0; r < 4; ++r) {
      hqr[r] = __shfl(hq, q * 4 + r, 64);
      hkr[r] = __shfl(hk, q * 4 + r, 64);
    }

    float sc[4];
#pragma unroll
    for (int r = 0; r < 4; ++r) {
      float mx = cq[0][r];
#pragma unroll
      for (int t = 1; t < 16; ++t) mx = fmaxf(mx, cq[t][r]);
#pragma unroll
      for (int m = 1; m <= 8; m <<= 1) mx = fmaxf(mx, __shfl_xor(mx, m, 64));
      float wsum = 0.f, nsum = 0.f;
#pragma unroll
      for (int t = 0; t < 16; ++t) {
        float qp = __expf(cq[t][r] - hqr[r] - mx) + 1e-4f;      // Qp * 16
        float kp = __expf(ck[t][r] - hkr[r] - Mglob) + 1e-4f;   // Kp * 16
        wsum += qp * kp;
        nsum += qp * S_lds[t * 16 + c];
      }
#pragma unroll
      for (int m = 1; m <= 8; m <<= 1) {
        wsum += __shfl_xor(wsum, m, 64);
        nsum += __shfl_xor(nsum, m, 64);
      }
      sc[r] = (wsum * (1.f / 256.f)) / (nsum * 0.0625f + 1e-8f);
    }

    // wave-local epilogue: scale this wave's 16 rows of V
    float4* op = (float4*)out + f4base;
#pragma unroll
    for (int i = 0; i < 8; ++i) {
      // rows rr = 2i (lanes 0-31) and 2i+1 (lanes 32-63); scale(rr) lives in
      // quarter rr>>2, register sc[rr&3]
      float s_lo = __shfl(sc[(2 * i) & 3], ((2 * i) >> 2) << 4, 64);
      float s_hi = __shfl(sc[(2 * i + 1) & 3], ((2 * i + 1) >> 2) << 4, 64);
      float s = (lane < 32) ? s_lo : s_hi;
      float4 v = vf[i];
      op[i * 64 + lane] = make_float4(v.x * s, v.y * s, v.z * s, v.w * s);
    }
  }
}

// ---------------------------------------------------------------------------
extern "C" void kernel_launch(void* const* d_in, const int* in_sizes, int n_in,
                              void* d_out, int out_size, void* d_ws, size_t ws_size,
                              hipStream_t stream) {
  const float* Q  = (const float*)d_in[0];
  const float* K  = (const float*)d_in[1];
  const float* V  = (const float*)d_in[2];
  const float* om = (const float*)d_in[3];
  float* out = (float*)d_out;
  int N = in_sizes[0] / D_QK;               // 262144
  int nblk = N / 64;                        // 4096
  int T = nblk / GBLK;                      // 8 tiles per persistent block
  int NG = GBLK * 4;                        // 2048 wave groups

  // ws layout (bytes): omt[65536] | Lout[NG*4] | Pout[NG*256*4] | S[1024] | Mkey | Mout
  char* ws = (char*)d_ws;
  _Float16* omt = (_Float16*)ws;
  size_t off = (size_t)OMT_HALVES * 2;                // 65536
  float* Lout = (float*)(ws + off);   off += (size_t)NG * 4;
  float* Pout = (float*)(ws + off);   off += (size_t)NG * 256 * 4;
  float* S    = (float*)(ws + off);   off += 1024;
  unsigned* Mkey = (unsigned*)(ws + off); off += 16;
  float* Mout = (float*)(ws + off);

  hipLaunchKernelGGL(k_prep, dim3((OMT_HALVES + 255) / 256), dim3(256), 0, stream,
                     om, omt, S, Mkey);
  hipLaunchKernelGGL(k_kstats, dim3(GBLK), dim3(256), 0, stream, K, omt, Lout, Pout, Mkey, T);
  hipLaunchKernelGGL(k_combine, dim3(NG / 32), dim3(256), 0, stream, Lout, Pout, Mkey, Mout, S);
  hipLaunchKernelGGL(k_main, dim3(GBLK), dim3(256), 0, stream, Q, K, V, omt, S, Mout, out,
                     (float)N * 1e-4f, T);
}